// Round 15
// baseline (153.769 us; speedup 1.0000x reference)
//
#include <hip/hip_runtime.h>

typedef __attribute__((ext_vector_type(8))) short short8;
typedef __attribute__((ext_vector_type(4))) float f32x4;

#define N_NODES 100000
#define N_EDGES 1600000
#define IN_F 128
#define OUT_ALL 64   // HEADS*OUT_F
#define HEADS 4
#define OUT_F 16
#define NTILES (N_NODES / 16)          // 6250
#define BIN_BLOCKS 250
#define EPB (N_EDGES / BIN_BLOCKS)     // 6400 edges per bin block
#define TOTAL_BLOCKS 2048
#define PROJ_BLOCKS (TOTAL_BLOCKS - BIN_BLOCKS)   // 1798
#define SLICE_SHIFT 8
#define SLICE_NODES 256
#define NSLICES ((N_NODES + SLICE_NODES - 1) / SLICE_NODES)   // 391
#define SEG_CAP 4608                   // avg 4096 + 8 sigma
#define NCHUNKS (NSLICES * 4)          // 1564 chunks of 64 nodes
#define SORT_CAPQ 1280                 // chunk: avg 1024 + 8 sigma

static __device__ __forceinline__ ushort f2bf(float f) {
    unsigned u = __float_as_uint(f);
    return (ushort)((u + 0x7FFF + ((u >> 16) & 1)) >> 16);   // RN, no NaN inputs
}
static __device__ __forceinline__ float bf2f(ushort b) {
    return __uint_as_float(((unsigned)b) << 16);
}
static __device__ __forceinline__ short8 pack_bf16x8(float4 f0, float4 f1) {
    union { unsigned u[4]; short8 s; } r;
    asm("v_cvt_pk_bf16_f32 %0, %1, %2" : "=v"(r.u[0]) : "v"(f0.x), "v"(f0.y));
    asm("v_cvt_pk_bf16_f32 %0, %1, %2" : "=v"(r.u[1]) : "v"(f0.z), "v"(f0.w));
    asm("v_cvt_pk_bf16_f32 %0, %1, %2" : "=v"(r.u[2]) : "v"(f1.x), "v"(f1.y));
    asm("v_cvt_pk_bf16_f32 %0, %1, %2" : "=v"(r.u[3]) : "v"(f1.z), "v"(f1.w));
    return r.s;
}

// ---- Kernel 0: fold att into W + zero scursor ----------------------------
__global__ __launch_bounds__(256) void prep_kernel(
    const float* __restrict__ W, const float* __restrict__ att_i,
    const float* __restrict__ att_j, float* __restrict__ wiwj,
    int* __restrict__ scursor)
{
    int idx = blockIdx.x * 256 + threadIdx.x;
    if (idx < NSLICES) scursor[idx] = 0;
    if (idx >= IN_F * 8) return;
    int k = idx >> 3, c = idx & 7;
    int h = c & 3;
    const float* att = (c < 4) ? att_i : att_j;
    float s = 0.f;
    #pragma unroll
    for (int f = 0; f < 16; ++f)
        s += W[(size_t)(h * 16 + f) * IN_F + k] * att[h * OUT_F + f];
    wiwj[k * 8 + c] = s;
}

// ---- Kernel 1: fused MFMA projection + slice binning ---------------------
// Proj: LDS-staged x tile (R14-proven); stores now HEAD-MAJOR:
//   hbg[h][node][16] bf16, aih[h][node], ajh[h][node] f32 — so the agg
//   phase's per-XCD random working set (3.2+0.4+0.4 MB) fits one L2.
// Bin: packed 4B entries (src<<8 | dst&255) — seg traffic halves.
__global__ __launch_bounds__(256) void proj_bin_kernel(
    const float* __restrict__ x, const float* __restrict__ W,
    const float* __restrict__ wiwj, const int* __restrict__ ei,
    ushort* __restrict__ hbg, float* __restrict__ aih, float* __restrict__ ajh,
    int* __restrict__ scursor, int* __restrict__ seg)
{
    __shared__ int cnt[NSLICES];              // 1.6 KB
    __shared__ int gbase[NSLICES];            // 1.6 KB
    __shared__ int run[NSLICES];              // 1.6 KB
    __shared__ float xs[16][129];             // 8.3 KB

    if (blockIdx.x < BIN_BLOCKS) {
        int base = blockIdx.x * EPB;
        const int4* __restrict__ srcp = (const int4*)(ei + base);
        const int4* __restrict__ dstp = (const int4*)(ei + N_EDGES + base);
        for (int s = threadIdx.x; s < NSLICES; s += 256) { cnt[s] = 0; run[s] = 0; }
        __syncthreads();
        for (int i = threadIdx.x; i < EPB / 4; i += 256) {
            int4 d = dstp[i];
            atomicAdd(&cnt[d.x >> SLICE_SHIFT], 1);
            atomicAdd(&cnt[d.y >> SLICE_SHIFT], 1);
            atomicAdd(&cnt[d.z >> SLICE_SHIFT], 1);
            atomicAdd(&cnt[d.w >> SLICE_SHIFT], 1);
        }
        __syncthreads();
        for (int s = threadIdx.x; s < NSLICES; s += 256) {
            int c = cnt[s];
            gbase[s] = c ? atomicAdd(&scursor[s], c) : 0;
        }
        __syncthreads();
        for (int i = threadIdx.x; i < EPB / 4; i += 256) {
            int4 sv = srcp[i];
            int4 dv = dstp[i];
            int ss, p;
            ss = dv.x >> SLICE_SHIFT; p = gbase[ss] + atomicAdd(&run[ss], 1);
            if (p < SEG_CAP) seg[(size_t)ss * SEG_CAP + p] = (sv.x << 8) | (dv.x & 255);
            ss = dv.y >> SLICE_SHIFT; p = gbase[ss] + atomicAdd(&run[ss], 1);
            if (p < SEG_CAP) seg[(size_t)ss * SEG_CAP + p] = (sv.y << 8) | (dv.y & 255);
            ss = dv.z >> SLICE_SHIFT; p = gbase[ss] + atomicAdd(&run[ss], 1);
            if (p < SEG_CAP) seg[(size_t)ss * SEG_CAP + p] = (sv.z << 8) | (dv.z & 255);
            ss = dv.w >> SLICE_SHIFT; p = gbase[ss] + atomicAdd(&run[ss], 1);
            if (p < SEG_CAP) seg[(size_t)ss * SEG_CAP + p] = (sv.w << 8) | (dv.w & 255);
        }
        return;
    }

    int bproj = blockIdx.x - BIN_BLOCKS;       // 0..1797
    const int nproj = PROJ_BLOCKS;

    int w   = threadIdx.x >> 6;    // wave id == head == 16-col n-tile
    int l   = threadIdx.x & 63;
    int col = l & 15;
    int kg  = l >> 4;              // k-group 0..3 (8 k each)

    short8 bw[4];
    #pragma unroll
    for (int m = 0; m < 4; ++m) {
        const float* wp = W + (size_t)(w * 16 + col) * IN_F + m * 32 + kg * 8;
        float4 f0 = *(const float4*)wp;
        float4 f1 = *(const float4*)(wp + 4);
        bw[m] = pack_bf16x8(f0, f1);
    }
    short8 bwd[4];
    #pragma unroll
    for (int m = 0; m < 4; ++m) {
        float v[8];
        #pragma unroll
        for (int j = 0; j < 8; ++j)
            v[j] = (col < 8) ? wiwj[(size_t)(m * 32 + kg * 8 + j) * 8 + col] : 0.f;
        bwd[m] = pack_bf16x8(float4{v[0], v[1], v[2], v[3]},
                             float4{v[4], v[5], v[6], v[7]});
    }

    for (int t = bproj; t < NTILES; t += nproj) {
        int nodeBase = t * 16;

        __syncthreads();
        #pragma unroll
        for (int r = 0; r < 2; ++r) {
            int chunk = threadIdx.x + r * 256;     // 0..511
            int row = chunk >> 5, c4 = chunk & 31;
            float4 v = *(const float4*)(x + (size_t)(nodeBase + row) * IN_F + c4 * 4);
            xs[row][c4 * 4 + 0] = v.x;
            xs[row][c4 * 4 + 1] = v.y;
            xs[row][c4 * 4 + 2] = v.z;
            xs[row][c4 * 4 + 3] = v.w;
        }
        __syncthreads();

        short8 a[4];
        #pragma unroll
        for (int m = 0; m < 4; ++m) {
            const float* xr = &xs[col][m * 32 + kg * 8];
            float4 f0 = {xr[0], xr[1], xr[2], xr[3]};
            float4 f1 = {xr[4], xr[5], xr[6], xr[7]};
            a[m] = pack_bf16x8(f0, f1);
        }
        f32x4 acc = {0.f, 0.f, 0.f, 0.f};
        f32x4 accd = {0.f, 0.f, 0.f, 0.f};
        #pragma unroll
        for (int m = 0; m < 4; ++m) {
            acc  = __builtin_amdgcn_mfma_f32_16x16x32_bf16(a[m], bw[m],  acc,  0, 0, 0);
            accd = __builtin_amdgcn_mfma_f32_16x16x32_bf16(a[m], bwd[m], accd, 0, 0, 0);
        }

        // head-major h store: hbg[w][node][col]
        #pragma unroll
        for (int r = 0; r < 4; ++r)
            hbg[((size_t)w * N_NODES + nodeBase + kg * 4 + r) * OUT_F + col] = f2bf(acc[r]);

        // head-major att dots (accd identical in all 4 waves; wave w stores head w)
        if (col == w) {
            #pragma unroll
            for (int r = 0; r < 4; ++r)
                aih[(size_t)w * N_NODES + nodeBase + kg * 4 + r] = accd[r];
        } else if (col == w + 4) {
            #pragma unroll
            for (int r = 0; r < 4; ++r)
                ajh[(size_t)w * N_NODES + nodeBase + kg * 4 + r] = accd[r];
        }
    }
}

// ---- Kernel 2: per-chunk counting sort (seg -> global sorted src list) ---
// Block = (slice s, quarter q) = 64-node chunk. Same proven sort as R13's
// agg front half, but writes sorted srcs + rowptr to GLOBAL so the 4
// head-partitioned agg passes don't re-sort.
__global__ __launch_bounds__(256) void sort_kernel(
    const int* __restrict__ seg, const int* __restrict__ scursor,
    int* __restrict__ srt, int* __restrict__ rowptrq)
{
    __shared__ int cnt[64];
    __shared__ int run[64];
    __shared__ int rowptr[65];

    int s = blockIdx.x >> 2;
    int q = blockIdx.x & 3;
    int total = scursor[s]; if (total > SEG_CAP) total = SEG_CAP;
    const int* sp = seg + (size_t)s * SEG_CAP;

    if (threadIdx.x < 64) { cnt[threadIdx.x] = 0; run[threadIdx.x] = 0; }
    __syncthreads();

    for (int i = threadIdx.x; i < total; i += 256) {
        int d8 = sp[i] & 255;
        if ((d8 >> 6) == q) atomicAdd(&cnt[d8 & 63], 1);
    }
    __syncthreads();

    if (threadIdx.x < 64) {
        int l = threadIdx.x;
        int v = cnt[l];
        int inc = v;
        #pragma unroll
        for (int d = 1; d < 64; d <<= 1) {
            int t = __shfl_up(inc, d, 64);
            if (l >= d) inc += t;
        }
        rowptr[l] = inc - v;
        if (l == 63) rowptr[64] = inc;
    }
    __syncthreads();

    for (int i = threadIdx.x; i < total; i += 256) {
        int e = sp[i];
        int d8 = e & 255;
        if ((d8 >> 6) == q) {
            int lb = d8 & 63;
            int p = rowptr[lb] + atomicAdd(&run[lb], 1);
            if (p < SORT_CAPQ) srt[(size_t)blockIdx.x * SORT_CAPQ + p] = (unsigned)e >> 8;
        }
    }
    __syncthreads();

    if (threadIdx.x < 65) {
        int v = rowptr[threadIdx.x];
        rowptrq[(size_t)blockIdx.x * 65 + threadIdx.x] = v > SORT_CAPQ ? SORT_CAPQ : v;
    }
}

// ---- Kernel 3: head-partitioned gather (XCD-pinned random reads) ---------
// Block = (chunk, head), head = blockIdx&3 -> round-robin dispatch pins each
// head to 2 XCDs whose L2 holds that head's hbg slice (3.2MB) + ajh (0.4MB).
// 4 lanes/node; per edge: broadcast src + ajh, one 8B hbg load/lane. No LDS.
__global__ __launch_bounds__(256) void agg_kernel(
    const int* __restrict__ srt, const int* __restrict__ rowptrq,
    const ushort* __restrict__ hbg, const float* __restrict__ aih,
    const float* __restrict__ ajh, float* __restrict__ out)
{
    int chunk = blockIdx.x >> 2;
    int head  = blockIdx.x & 3;
    int g     = threadIdx.x >> 2;   // 0..63 local node
    int lane  = threadIdx.x & 3;    // 4 feats each
    int node  = chunk * 64 + g;
    if (node >= N_NODES) return;

    const int* rp = rowptrq + (size_t)chunk * 65;
    int beg = rp[g], end = rp[g + 1];
    const int* sb = srt + (size_t)chunk * SORT_CAPQ;
    const ushort* hb_h = hbg + (size_t)head * N_NODES * OUT_F;
    const float*  aj_h = ajh + (size_t)head * N_NODES;

    float aiv = aih[(size_t)head * N_NODES + node];
    float4 acc = {0.f, 0.f, 0.f, 0.f};
    float  den = 0.f;
    for (int k = beg; k < end; ++k) {
        int src = sb[k];                        // broadcast across 4 lanes
        float av = aiv + aj_h[src];
        av = av > 0.f ? av : 0.01f * av;
        float ex = __expf(av);
        den += ex;
        ushort4 hv = *(const ushort4*)(hb_h + (size_t)src * OUT_F + lane * 4);
        acc.x += ex * bf2f(hv.x); acc.y += ex * bf2f(hv.y);
        acc.z += ex * bf2f(hv.z); acc.w += ex * bf2f(hv.w);
    }
    float inv = 1.0f / (den + 1e-16f);
    acc.x *= inv; acc.y *= inv; acc.z *= inv; acc.w *= inv;
    *(float4*)(out + (size_t)node * OUT_ALL + head * OUT_F + lane * 4) = acc;
}

extern "C" void kernel_launch(void* const* d_in, const int* in_sizes, int n_in,
                              void* d_out, int out_size, void* d_ws, size_t ws_size,
                              hipStream_t stream) {
    const float* x     = (const float*)d_in[0];
    const int*   ei    = (const int*)d_in[1];
    const float* W     = (const float*)d_in[2];
    const float* att_i = (const float*)d_in[3];
    const float* att_j = (const float*)d_in[4];
    float* out = (float*)d_out;

    char* ws = (char*)d_ws;
    size_t off = 0;
    auto alloc = [&](size_t bytes) {
        void* p = ws + off;
        off += (bytes + 255) & ~(size_t)255;
        return p;
    };
    ushort* hbg     = (ushort*)alloc((size_t)HEADS * N_NODES * OUT_F * 2); // 12.8 MB
    float*  aih     = (float*)alloc((size_t)HEADS * N_NODES * 4);          // 1.6 MB
    float*  ajh     = (float*)alloc((size_t)HEADS * N_NODES * 4);          // 1.6 MB
    float*  wiwj    = (float*)alloc((size_t)IN_F * 8 * 4);                 // 4 KB
    int*    scursor = (int*)alloc((size_t)NSLICES * 4);                    // 1.6 KB
    int*    seg     = (int*)alloc((size_t)NSLICES * SEG_CAP * 4);          // 7.2 MB
    int*    srt     = (int*)alloc((size_t)NCHUNKS * SORT_CAPQ * 4);        // 8.0 MB
    int*    rowptrq = (int*)alloc((size_t)NCHUNKS * 65 * 4);               // 0.4 MB

    prep_kernel<<<(IN_F * 8 + 255) / 256, 256, 0, stream>>>(
        W, att_i, att_j, wiwj, scursor);
    proj_bin_kernel<<<TOTAL_BLOCKS, 256, 0, stream>>>(
        x, W, wiwj, ei, hbg, aih, ajh, scursor, seg);
    sort_kernel<<<NCHUNKS, 256, 0, stream>>>(seg, scursor, srt, rowptrq);
    agg_kernel<<<NCHUNKS * 4, 256, 0, stream>>>(srt, rowptrq, hbg, aih, ajh, out);
}

// Round 16
// 94.372 us; speedup vs baseline: 1.6294x; 1.6294x over previous
//
#include <hip/hip_runtime.h>

typedef __attribute__((ext_vector_type(8))) short short8;
typedef __attribute__((ext_vector_type(4))) float f32x4;

#define N_NODES 100000
#define N_EDGES 1600000
#define IN_F 128
#define OUT_ALL 64   // HEADS*OUT_F
#define HEADS 4
#define OUT_F 16
#define NTILES (N_NODES / 16)          // 6250
#define BIN_BLOCKS 250
#define EPB (N_EDGES / BIN_BLOCKS)     // 6400 edges per bin block
#define TOTAL_BLOCKS 2048
#define PROJ_BLOCKS (TOTAL_BLOCKS - BIN_BLOCKS)   // 1798
#define SLICE_SHIFT 8
#define SLICE_NODES 256
#define NSLICES ((N_NODES + SLICE_NODES - 1) / SLICE_NODES)   // 391
#define SEG_CAP 4608                   // avg 4096 + 8 sigma
#define QUARTER_NODES 64
#define SORT_CAP 1280                  // quarter: avg 1024 + 8 sigma

static __device__ __forceinline__ ushort f2bf(float f) {
    unsigned u = __float_as_uint(f);
    return (ushort)((u + 0x7FFF + ((u >> 16) & 1)) >> 16);   // RN, no NaN inputs
}
static __device__ __forceinline__ float bf2f(ushort b) {
    return __uint_as_float(((unsigned)b) << 16);
}
static __device__ __forceinline__ float lrelu(float v) {
    return v > 0.f ? v : 0.01f * v;
}
static __device__ __forceinline__ short8 pack_bf16x8(float4 f0, float4 f1) {
    union { unsigned u[4]; short8 s; } r;
    asm("v_cvt_pk_bf16_f32 %0, %1, %2" : "=v"(r.u[0]) : "v"(f0.x), "v"(f0.y));
    asm("v_cvt_pk_bf16_f32 %0, %1, %2" : "=v"(r.u[1]) : "v"(f0.z), "v"(f0.w));
    asm("v_cvt_pk_bf16_f32 %0, %1, %2" : "=v"(r.u[2]) : "v"(f1.x), "v"(f1.y));
    asm("v_cvt_pk_bf16_f32 %0, %1, %2" : "=v"(r.u[3]) : "v"(f1.z), "v"(f1.w));
    return r.s;
}

// ---- Kernel 0: fold att into W + zero scursor ----------------------------
__global__ __launch_bounds__(256) void prep_kernel(
    const float* __restrict__ W, const float* __restrict__ att_i,
    const float* __restrict__ att_j, float* __restrict__ wiwj,
    int* __restrict__ scursor)
{
    int idx = blockIdx.x * 256 + threadIdx.x;
    if (idx < NSLICES) scursor[idx] = 0;
    if (idx >= IN_F * 8) return;
    int k = idx >> 3, c = idx & 7;
    int h = c & 3;
    const float* att = (c < 4) ? att_i : att_j;
    float s = 0.f;
    #pragma unroll
    for (int f = 0; f < 16; ++f)
        s += W[(size_t)(h * 16 + f) * IN_F + k] * att[h * OUT_F + f];
    wiwj[k * 8 + c] = s;
}

// ---- Kernel 1: fused MFMA projection (LDS-staged x) + slice binning ------
// (byte-identical to R14: the best-measured configuration)
__global__ __launch_bounds__(256) void proj_bin_kernel(
    const float* __restrict__ x, const float* __restrict__ W,
    const float* __restrict__ wiwj, const int* __restrict__ ei,
    ushort* __restrict__ hb, float* __restrict__ ai, float* __restrict__ aj,
    int* __restrict__ scursor, int2* __restrict__ seg)
{
    __shared__ int cnt[NSLICES];              // 1.6 KB
    __shared__ int gbase[NSLICES];            // 1.6 KB
    __shared__ int run[NSLICES];              // 1.6 KB
    __shared__ float xs[16][129];             // 8.3 KB

    if (blockIdx.x < BIN_BLOCKS) {
        int base = blockIdx.x * EPB;
        const int4* __restrict__ srcp = (const int4*)(ei + base);
        const int4* __restrict__ dstp = (const int4*)(ei + N_EDGES + base);
        for (int s = threadIdx.x; s < NSLICES; s += 256) { cnt[s] = 0; run[s] = 0; }
        __syncthreads();
        for (int i = threadIdx.x; i < EPB / 4; i += 256) {
            int4 d = dstp[i];
            atomicAdd(&cnt[d.x >> SLICE_SHIFT], 1);
            atomicAdd(&cnt[d.y >> SLICE_SHIFT], 1);
            atomicAdd(&cnt[d.z >> SLICE_SHIFT], 1);
            atomicAdd(&cnt[d.w >> SLICE_SHIFT], 1);
        }
        __syncthreads();
        for (int s = threadIdx.x; s < NSLICES; s += 256) {
            int c = cnt[s];
            gbase[s] = c ? atomicAdd(&scursor[s], c) : 0;
        }
        __syncthreads();
        for (int i = threadIdx.x; i < EPB / 4; i += 256) {
            int4 sv = srcp[i];
            int4 dv = dstp[i];
            int ss, p;
            ss = dv.x >> SLICE_SHIFT; p = gbase[ss] + atomicAdd(&run[ss], 1);
            if (p < SEG_CAP) seg[(size_t)ss * SEG_CAP + p] = make_int2(sv.x, dv.x);
            ss = dv.y >> SLICE_SHIFT; p = gbase[ss] + atomicAdd(&run[ss], 1);
            if (p < SEG_CAP) seg[(size_t)ss * SEG_CAP + p] = make_int2(sv.y, dv.y);
            ss = dv.z >> SLICE_SHIFT; p = gbase[ss] + atomicAdd(&run[ss], 1);
            if (p < SEG_CAP) seg[(size_t)ss * SEG_CAP + p] = make_int2(sv.z, dv.z);
            ss = dv.w >> SLICE_SHIFT; p = gbase[ss] + atomicAdd(&run[ss], 1);
            if (p < SEG_CAP) seg[(size_t)ss * SEG_CAP + p] = make_int2(sv.w, dv.w);
        }
        return;
    }

    int bproj = blockIdx.x - BIN_BLOCKS;       // 0..1797
    const int nproj = PROJ_BLOCKS;

    int w   = threadIdx.x >> 6;    // wave id == head == 16-col n-tile
    int l   = threadIdx.x & 63;
    int col = l & 15;
    int kg  = l >> 4;              // k-group 0..3 (8 k each)

    short8 bw[4];
    #pragma unroll
    for (int m = 0; m < 4; ++m) {
        const float* wp = W + (size_t)(w * 16 + col) * IN_F + m * 32 + kg * 8;
        float4 f0 = *(const float4*)wp;
        float4 f1 = *(const float4*)(wp + 4);
        bw[m] = pack_bf16x8(f0, f1);
    }
    short8 bwd[4];
    #pragma unroll
    for (int m = 0; m < 4; ++m) {
        float v[8];
        #pragma unroll
        for (int j = 0; j < 8; ++j)
            v[j] = (col < 8) ? wiwj[(size_t)(m * 32 + kg * 8 + j) * 8 + col] : 0.f;
        bwd[m] = pack_bf16x8(float4{v[0], v[1], v[2], v[3]},
                             float4{v[4], v[5], v[6], v[7]});
    }

    for (int t = bproj; t < NTILES; t += nproj) {
        int nodeBase = t * 16;

        __syncthreads();
        #pragma unroll
        for (int r = 0; r < 2; ++r) {
            int chunk = threadIdx.x + r * 256;     // 0..511
            int row = chunk >> 5, c4 = chunk & 31;
            float4 v = *(const float4*)(x + (size_t)(nodeBase + row) * IN_F + c4 * 4);
            xs[row][c4 * 4 + 0] = v.x;
            xs[row][c4 * 4 + 1] = v.y;
            xs[row][c4 * 4 + 2] = v.z;
            xs[row][c4 * 4 + 3] = v.w;
        }
        __syncthreads();

        short8 a[4];
        #pragma unroll
        for (int m = 0; m < 4; ++m) {
            const float* xr = &xs[col][m * 32 + kg * 8];
            float4 f0 = {xr[0], xr[1], xr[2], xr[3]};
            float4 f1 = {xr[4], xr[5], xr[6], xr[7]};
            a[m] = pack_bf16x8(f0, f1);
        }
        f32x4 acc = {0.f, 0.f, 0.f, 0.f};
        f32x4 accd = {0.f, 0.f, 0.f, 0.f};
        #pragma unroll
        for (int m = 0; m < 4; ++m) {
            acc  = __builtin_amdgcn_mfma_f32_16x16x32_bf16(a[m], bw[m],  acc,  0, 0, 0);
            accd = __builtin_amdgcn_mfma_f32_16x16x32_bf16(a[m], bwd[m], accd, 0, 0, 0);
        }

        #pragma unroll
        for (int r = 0; r < 4; ++r)
            hb[(size_t)(nodeBase + kg * 4 + r) * OUT_ALL + w * 16 + col] = f2bf(acc[r]);

        if (col < 4) {
            #pragma unroll
            for (int r = 0; r < 4; ++r)
                ai[(size_t)(nodeBase + kg * 4 + r) * HEADS + col] = accd[r];
        } else if (col < 8) {
            #pragma unroll
            for (int r = 0; r < 4; ++r)
                aj[(size_t)(nodeBase + kg * 4 + r) * HEADS + (col - 4)] = accd[r];
        }
    }
}

// ---- Kernel 2: quarter-slice counting-sort + register gather -------------
// R14 structure; gather loop unrolled 4x: batch 4 srcs from LDS, issue
// 4 aj + 4 hb loads back-to-back (4x memory-level parallelism), then
// consume. Attacks the measured latency-bound profile (VALUBusy 27%).
__global__ __launch_bounds__(512) void agg_kernel(
    const int2* __restrict__ seg, const int* __restrict__ scursor,
    const ushort* __restrict__ hb, const float* __restrict__ ai,
    const float* __restrict__ aj, float* __restrict__ out)
{
    __shared__ int sorted_src[SORT_CAP];      // 5.1 KB
    __shared__ int cnt[QUARTER_NODES];
    __shared__ int run[QUARTER_NODES];
    __shared__ int rowptr[QUARTER_NODES + 1];

    int s       = blockIdx.x >> 2;
    int quarter = blockIdx.x & 3;
    int nbase   = (s << SLICE_SHIFT) + quarter * QUARTER_NODES;
    int total = scursor[s]; if (total > SEG_CAP) total = SEG_CAP;
    const int2* sp = seg + (size_t)s * SEG_CAP;

    for (int i = threadIdx.x; i < QUARTER_NODES; i += 512) { cnt[i] = 0; run[i] = 0; }
    __syncthreads();

    for (int i = threadIdx.x; i < total; i += 512) {
        int d = sp[i].y & (SLICE_NODES - 1);
        if ((d >> 6) == quarter) atomicAdd(&cnt[d & (QUARTER_NODES - 1)], 1);
    }
    __syncthreads();

    if (threadIdx.x < 64) {
        int l = threadIdx.x;
        int v = cnt[l];
        int inc = v;
        #pragma unroll
        for (int d = 1; d < 64; d <<= 1) {
            int t = __shfl_up(inc, d, 64);
            if (l >= d) inc += t;
        }
        rowptr[l] = inc - v;
        if (l == 63) rowptr[64] = inc;
    }
    __syncthreads();

    for (int i = threadIdx.x; i < total; i += 512) {
        int2 e = sp[i];
        int d = e.y & (SLICE_NODES - 1);
        if ((d >> 6) == quarter) {
            int lb = d & (QUARTER_NODES - 1);
            int p = rowptr[lb] + atomicAdd(&run[lb], 1);
            if (p < SORT_CAP) sorted_src[p] = e.x;
        }
    }
    __syncthreads();

    int g    = threadIdx.x >> 3;   // 0..63 == local node
    int sub  = threadIdx.x & 7;    // 8 lanes, 8 cols each
    int head = sub >> 1;
    int node = nbase + g;
    if (node >= N_NODES) return;
    int beg = rowptr[g], end = rowptr[g + 1];
    if (end > SORT_CAP) end = SORT_CAP;
    float aiv = ai[(size_t)node * HEADS + head];
    float acc[8] = {0.f, 0.f, 0.f, 0.f, 0.f, 0.f, 0.f, 0.f};
    float den = 0.f;

    int k = beg;
    for (; k + 4 <= end; k += 4) {
        int s0 = sorted_src[k + 0];
        int s1 = sorted_src[k + 1];
        int s2 = sorted_src[k + 2];
        int s3 = sorted_src[k + 3];
        float aj0 = aj[(size_t)s0 * HEADS + head];
        float aj1 = aj[(size_t)s1 * HEADS + head];
        float aj2 = aj[(size_t)s2 * HEADS + head];
        float aj3 = aj[(size_t)s3 * HEADS + head];
        short8 h0 = *(const short8*)(hb + (size_t)s0 * OUT_ALL + sub * 8);
        short8 h1 = *(const short8*)(hb + (size_t)s1 * OUT_ALL + sub * 8);
        short8 h2 = *(const short8*)(hb + (size_t)s2 * OUT_ALL + sub * 8);
        short8 h3 = *(const short8*)(hb + (size_t)s3 * OUT_ALL + sub * 8);
        float e0 = __expf(lrelu(aiv + aj0));
        float e1 = __expf(lrelu(aiv + aj1));
        float e2 = __expf(lrelu(aiv + aj2));
        float e3 = __expf(lrelu(aiv + aj3));
        den += (e0 + e1) + (e2 + e3);
        #pragma unroll
        for (int q = 0; q < 8; ++q)
            acc[q] += e0 * bf2f((ushort)h0[q]) + e1 * bf2f((ushort)h1[q]) +
                      e2 * bf2f((ushort)h2[q]) + e3 * bf2f((ushort)h3[q]);
    }
    for (; k < end; ++k) {
        int src = sorted_src[k];
        float ex = __expf(lrelu(aiv + aj[(size_t)src * HEADS + head]));
        den += ex;
        short8 hv = *(const short8*)(hb + (size_t)src * OUT_ALL + sub * 8);
        #pragma unroll
        for (int q = 0; q < 8; ++q)
            acc[q] += ex * bf2f((ushort)hv[q]);
    }

    float inv = 1.0f / (den + 1e-16f);
    float4 o0 = {acc[0] * inv, acc[1] * inv, acc[2] * inv, acc[3] * inv};
    float4 o1 = {acc[4] * inv, acc[5] * inv, acc[6] * inv, acc[7] * inv};
    float* op = out + (size_t)node * OUT_ALL + sub * 8;
    *(float4*)op = o0;
    *(float4*)(op + 4) = o1;
}

extern "C" void kernel_launch(void* const* d_in, const int* in_sizes, int n_in,
                              void* d_out, int out_size, void* d_ws, size_t ws_size,
                              hipStream_t stream) {
    const float* x     = (const float*)d_in[0];
    const int*   ei    = (const int*)d_in[1];
    const float* W     = (const float*)d_in[2];
    const float* att_i = (const float*)d_in[3];
    const float* att_j = (const float*)d_in[4];
    float* out = (float*)d_out;

    char* ws = (char*)d_ws;
    size_t off = 0;
    auto alloc = [&](size_t bytes) {
        void* p = ws + off;
        off += (bytes + 255) & ~(size_t)255;
        return p;
    };
    ushort* hb      = (ushort*)alloc((size_t)N_NODES * OUT_ALL * 2);   // 12.8 MB
    float*  ai      = (float*)alloc((size_t)N_NODES * HEADS * 4);      // 1.6 MB
    float*  aj      = (float*)alloc((size_t)N_NODES * HEADS * 4);      // 1.6 MB
    float*  wiwj    = (float*)alloc((size_t)IN_F * 8 * 4);             // 4 KB
    int*    scursor = (int*)alloc((size_t)NSLICES * 4);                // 1.6 KB
    int2*   seg     = (int2*)alloc((size_t)NSLICES * SEG_CAP * 8);     // 14.4 MB

    prep_kernel<<<(IN_F * 8 + 255) / 256, 256, 0, stream>>>(
        W, att_i, att_j, wiwj, scursor);
    proj_bin_kernel<<<TOTAL_BLOCKS, 256, 0, stream>>>(
        x, W, wiwj, ei, hb, ai, aj, scursor, seg);
    agg_kernel<<<NSLICES * 4, 512, 0, stream>>>(seg, scursor, hb, ai, aj, out);
}

// Round 17
// 93.004 us; speedup vs baseline: 1.6534x; 1.0147x over previous
//
#include <hip/hip_runtime.h>

typedef __attribute__((ext_vector_type(8))) short short8;
typedef __attribute__((ext_vector_type(4))) float f32x4;

#define N_NODES 100000
#define N_EDGES 1600000
#define IN_F 128
#define OUT_ALL 64   // HEADS*OUT_F
#define HEADS 4
#define OUT_F 16
#define NTILES (N_NODES / 16)          // 6250
#define BIN_BLOCKS 250
#define EPB (N_EDGES / BIN_BLOCKS)     // 6400 edges per bin block
#define TOTAL_BLOCKS 2048
#define PROJ_BLOCKS (TOTAL_BLOCKS - BIN_BLOCKS)   // 1798
#define SLICE_SHIFT 8
#define SLICE_NODES 256
#define NSLICES ((N_NODES + SLICE_NODES - 1) / SLICE_NODES)   // 391
#define SEG_CAP 4608                   // avg 4096 + 8 sigma
#define QUARTER_NODES 64
#define SORT_CAP 1280                  // quarter: avg 1024 + 8 sigma

static __device__ __forceinline__ ushort f2bf(float f) {
    unsigned u = __float_as_uint(f);
    return (ushort)((u + 0x7FFF + ((u >> 16) & 1)) >> 16);   // RN, no NaN inputs
}
static __device__ __forceinline__ float bf2f(ushort b) {
    return __uint_as_float(((unsigned)b) << 16);
}
static __device__ __forceinline__ float lrelu(float v) {
    return v > 0.f ? v : 0.01f * v;
}
static __device__ __forceinline__ short8 pack_bf16x8(float4 f0, float4 f1) {
    union { unsigned u[4]; short8 s; } r;
    asm("v_cvt_pk_bf16_f32 %0, %1, %2" : "=v"(r.u[0]) : "v"(f0.x), "v"(f0.y));
    asm("v_cvt_pk_bf16_f32 %0, %1, %2" : "=v"(r.u[1]) : "v"(f0.z), "v"(f0.w));
    asm("v_cvt_pk_bf16_f32 %0, %1, %2" : "=v"(r.u[2]) : "v"(f1.x), "v"(f1.y));
    asm("v_cvt_pk_bf16_f32 %0, %1, %2" : "=v"(r.u[3]) : "v"(f1.z), "v"(f1.w));
    return r.s;
}

// ---- Kernel 0: fold att into W + zero scursor ----------------------------
__global__ __launch_bounds__(256) void prep_kernel(
    const float* __restrict__ W, const float* __restrict__ att_i,
    const float* __restrict__ att_j, float* __restrict__ wiwj,
    int* __restrict__ scursor)
{
    int idx = blockIdx.x * 256 + threadIdx.x;
    if (idx < NSLICES) scursor[idx] = 0;
    if (idx >= IN_F * 8) return;
    int k = idx >> 3, c = idx & 7;
    int h = c & 3;
    const float* att = (c < 4) ? att_i : att_j;
    float s = 0.f;
    #pragma unroll
    for (int f = 0; f < 16; ++f)
        s += W[(size_t)(h * 16 + f) * IN_F + k] * att[h * OUT_F + f];
    wiwj[k * 8 + c] = s;
}

// ---- Kernel 1: fused MFMA projection (bf16-LDS x) + slice binning --------
// Proj: stage the 16x128 x-tile ONCE as bf16 (convert in the stager, one
// ds_write_b128/thread); A-frags = 4x ds_read_b128, fed to MFMA directly.
// Per thread per tile: 5 LDS ops vs 40, zero per-wave cvt vs 16 (R16).
// Bin: byte-identical to R16.
__global__ __launch_bounds__(256) void proj_bin_kernel(
    const float* __restrict__ x, const float* __restrict__ W,
    const float* __restrict__ wiwj, const int* __restrict__ ei,
    ushort* __restrict__ hb, float* __restrict__ ai, float* __restrict__ aj,
    int* __restrict__ scursor, int2* __restrict__ seg)
{
    __shared__ int cnt[NSLICES];              // 1.6 KB
    __shared__ int gbase[NSLICES];            // 1.6 KB
    __shared__ int run[NSLICES];              // 1.6 KB
    __shared__ __align__(16) ushort xsb[16][144];  // bf16 tile, 288B pitch, 4.6 KB

    if (blockIdx.x < BIN_BLOCKS) {
        int base = blockIdx.x * EPB;
        const int4* __restrict__ srcp = (const int4*)(ei + base);
        const int4* __restrict__ dstp = (const int4*)(ei + N_EDGES + base);
        for (int s = threadIdx.x; s < NSLICES; s += 256) { cnt[s] = 0; run[s] = 0; }
        __syncthreads();
        for (int i = threadIdx.x; i < EPB / 4; i += 256) {
            int4 d = dstp[i];
            atomicAdd(&cnt[d.x >> SLICE_SHIFT], 1);
            atomicAdd(&cnt[d.y >> SLICE_SHIFT], 1);
            atomicAdd(&cnt[d.z >> SLICE_SHIFT], 1);
            atomicAdd(&cnt[d.w >> SLICE_SHIFT], 1);
        }
        __syncthreads();
        for (int s = threadIdx.x; s < NSLICES; s += 256) {
            int c = cnt[s];
            gbase[s] = c ? atomicAdd(&scursor[s], c) : 0;
        }
        __syncthreads();
        for (int i = threadIdx.x; i < EPB / 4; i += 256) {
            int4 sv = srcp[i];
            int4 dv = dstp[i];
            int ss, p;
            ss = dv.x >> SLICE_SHIFT; p = gbase[ss] + atomicAdd(&run[ss], 1);
            if (p < SEG_CAP) seg[(size_t)ss * SEG_CAP + p] = make_int2(sv.x, dv.x);
            ss = dv.y >> SLICE_SHIFT; p = gbase[ss] + atomicAdd(&run[ss], 1);
            if (p < SEG_CAP) seg[(size_t)ss * SEG_CAP + p] = make_int2(sv.y, dv.y);
            ss = dv.z >> SLICE_SHIFT; p = gbase[ss] + atomicAdd(&run[ss], 1);
            if (p < SEG_CAP) seg[(size_t)ss * SEG_CAP + p] = make_int2(sv.z, dv.z);
            ss = dv.w >> SLICE_SHIFT; p = gbase[ss] + atomicAdd(&run[ss], 1);
            if (p < SEG_CAP) seg[(size_t)ss * SEG_CAP + p] = make_int2(sv.w, dv.w);
        }
        return;
    }

    int bproj = blockIdx.x - BIN_BLOCKS;       // 0..1797
    const int nproj = PROJ_BLOCKS;

    int w   = threadIdx.x >> 6;    // wave id == head == 16-col n-tile
    int l   = threadIdx.x & 63;
    int col = l & 15;
    int kg  = l >> 4;              // k-group 0..3 (8 k each)

    short8 bw[4];
    #pragma unroll
    for (int m = 0; m < 4; ++m) {
        const float* wp = W + (size_t)(w * 16 + col) * IN_F + m * 32 + kg * 8;
        float4 f0 = *(const float4*)wp;
        float4 f1 = *(const float4*)(wp + 4);
        bw[m] = pack_bf16x8(f0, f1);
    }
    short8 bwd[4];
    #pragma unroll
    for (int m = 0; m < 4; ++m) {
        float v[8];
        #pragma unroll
        for (int j = 0; j < 8; ++j)
            v[j] = (col < 8) ? wiwj[(size_t)(m * 32 + kg * 8 + j) * 8 + col] : 0.f;
        bwd[m] = pack_bf16x8(float4{v[0], v[1], v[2], v[3]},
                             float4{v[4], v[5], v[6], v[7]});
    }

    // stager mapping: this thread fills row (tid>>4), 8-float chunk (tid&15)
    int srow = threadIdx.x >> 4;
    int sc8  = threadIdx.x & 15;

    for (int t = bproj; t < NTILES; t += nproj) {
        int nodeBase = t * 16;

        __syncthreads();   // protect xsb from previous-iteration readers
        {
            const float* xp = x + (size_t)(nodeBase + srow) * IN_F + sc8 * 8;
            float4 f0 = *(const float4*)xp;
            float4 f1 = *(const float4*)(xp + 4);
            *(short8*)&xsb[srow][sc8 * 8] = pack_bf16x8(f0, f1);
        }
        __syncthreads();

        // A-frags: one ds_read_b128 per K-block, fed to MFMA directly
        short8 a[4];
        #pragma unroll
        for (int m = 0; m < 4; ++m)
            a[m] = *(const short8*)&xsb[col][m * 32 + kg * 8];

        f32x4 acc = {0.f, 0.f, 0.f, 0.f};
        f32x4 accd = {0.f, 0.f, 0.f, 0.f};
        #pragma unroll
        for (int m = 0; m < 4; ++m) {
            acc  = __builtin_amdgcn_mfma_f32_16x16x32_bf16(a[m], bw[m],  acc,  0, 0, 0);
            accd = __builtin_amdgcn_mfma_f32_16x16x32_bf16(a[m], bwd[m], accd, 0, 0, 0);
        }

        #pragma unroll
        for (int r = 0; r < 4; ++r)
            hb[(size_t)(nodeBase + kg * 4 + r) * OUT_ALL + w * 16 + col] = f2bf(acc[r]);

        if (col < 4) {
            #pragma unroll
            for (int r = 0; r < 4; ++r)
                ai[(size_t)(nodeBase + kg * 4 + r) * HEADS + col] = accd[r];
        } else if (col < 8) {
            #pragma unroll
            for (int r = 0; r < 4; ++r)
                aj[(size_t)(nodeBase + kg * 4 + r) * HEADS + (col - 4)] = accd[r];
        }
    }
}

// ---- Kernel 2: quarter-slice counting-sort + register gather (R16) -------
__global__ __launch_bounds__(512) void agg_kernel(
    const int2* __restrict__ seg, const int* __restrict__ scursor,
    const ushort* __restrict__ hb, const float* __restrict__ ai,
    const float* __restrict__ aj, float* __restrict__ out)
{
    __shared__ int sorted_src[SORT_CAP];      // 5.1 KB
    __shared__ int cnt[QUARTER_NODES];
    __shared__ int run[QUARTER_NODES];
    __shared__ int rowptr[QUARTER_NODES + 1];

    int s       = blockIdx.x >> 2;
    int quarter = blockIdx.x & 3;
    int nbase   = (s << SLICE_SHIFT) + quarter * QUARTER_NODES;
    int total = scursor[s]; if (total > SEG_CAP) total = SEG_CAP;
    const int2* sp = seg + (size_t)s * SEG_CAP;

    for (int i = threadIdx.x; i < QUARTER_NODES; i += 512) { cnt[i] = 0; run[i] = 0; }
    __syncthreads();

    for (int i = threadIdx.x; i < total; i += 512) {
        int d = sp[i].y & (SLICE_NODES - 1);
        if ((d >> 6) == quarter) atomicAdd(&cnt[d & (QUARTER_NODES - 1)], 1);
    }
    __syncthreads();

    if (threadIdx.x < 64) {
        int l = threadIdx.x;
        int v = cnt[l];
        int inc = v;
        #pragma unroll
        for (int d = 1; d < 64; d <<= 1) {
            int t = __shfl_up(inc, d, 64);
            if (l >= d) inc += t;
        }
        rowptr[l] = inc - v;
        if (l == 63) rowptr[64] = inc;
    }
    __syncthreads();

    for (int i = threadIdx.x; i < total; i += 512) {
        int2 e = sp[i];
        int d = e.y & (SLICE_NODES - 1);
        if ((d >> 6) == quarter) {
            int lb = d & (QUARTER_NODES - 1);
            int p = rowptr[lb] + atomicAdd(&run[lb], 1);
            if (p < SORT_CAP) sorted_src[p] = e.x;
        }
    }
    __syncthreads();

    int g    = threadIdx.x >> 3;   // 0..63 == local node
    int sub  = threadIdx.x & 7;    // 8 lanes, 8 cols each
    int head = sub >> 1;
    int node = nbase + g;
    if (node >= N_NODES) return;
    int beg = rowptr[g], end = rowptr[g + 1];
    if (end > SORT_CAP) end = SORT_CAP;
    float aiv = ai[(size_t)node * HEADS + head];
    float acc[8] = {0.f, 0.f, 0.f, 0.f, 0.f, 0.f, 0.f, 0.f};
    float den = 0.f;

    int k = beg;
    for (; k + 4 <= end; k += 4) {
        int s0 = sorted_src[k + 0];
        int s1 = sorted_src[k + 1];
        int s2 = sorted_src[k + 2];
        int s3 = sorted_src[k + 3];
        float aj0 = aj[(size_t)s0 * HEADS + head];
        float aj1 = aj[(size_t)s1 * HEADS + head];
        float aj2 = aj[(size_t)s2 * HEADS + head];
        float aj3 = aj[(size_t)s3 * HEADS + head];
        short8 h0 = *(const short8*)(hb + (size_t)s0 * OUT_ALL + sub * 8);
        short8 h1 = *(const short8*)(hb + (size_t)s1 * OUT_ALL + sub * 8);
        short8 h2 = *(const short8*)(hb + (size_t)s2 * OUT_ALL + sub * 8);
        short8 h3 = *(const short8*)(hb + (size_t)s3 * OUT_ALL + sub * 8);
        float e0 = __expf(lrelu(aiv + aj0));
        float e1 = __expf(lrelu(aiv + aj1));
        float e2 = __expf(lrelu(aiv + aj2));
        float e3 = __expf(lrelu(aiv + aj3));
        den += (e0 + e1) + (e2 + e3);
        #pragma unroll
        for (int q = 0; q < 8; ++q)
            acc[q] += e0 * bf2f((ushort)h0[q]) + e1 * bf2f((ushort)h1[q]) +
                      e2 * bf2f((ushort)h2[q]) + e3 * bf2f((ushort)h3[q]);
    }
    for (; k < end; ++k) {
        int src = sorted_src[k];
        float ex = __expf(lrelu(aiv + aj[(size_t)src * HEADS + head]));
        den += ex;
        short8 hv = *(const short8*)(hb + (size_t)src * OUT_ALL + sub * 8);
        #pragma unroll
        for (int q = 0; q < 8; ++q)
            acc[q] += ex * bf2f((ushort)hv[q]);
    }

    float inv = 1.0f / (den + 1e-16f);
    float4 o0 = {acc[0] * inv, acc[1] * inv, acc[2] * inv, acc[3] * inv};
    float4 o1 = {acc[4] * inv, acc[5] * inv, acc[6] * inv, acc[7] * inv};
    float* op = out + (size_t)node * OUT_ALL + sub * 8;
    *(float4*)op = o0;
    *(float4*)(op + 4) = o1;
}

extern "C" void kernel_launch(void* const* d_in, const int* in_sizes, int n_in,
                              void* d_out, int out_size, void* d_ws, size_t ws_size,
                              hipStream_t stream) {
    const float* x     = (const float*)d_in[0];
    const int*   ei    = (const int*)d_in[1];
    const float* W     = (const float*)d_in[2];
    const float* att_i = (const float*)d_in[3];
    const float* att_j = (const float*)d_in[4];
    float* out = (float*)d_out;

    char* ws = (char*)d_ws;
    size_t off = 0;
    auto alloc = [&](size_t bytes) {
        void* p = ws + off;
        off += (bytes + 255) & ~(size_t)255;
        return p;
    };
    ushort* hb      = (ushort*)alloc((size_t)N_NODES * OUT_ALL * 2);   // 12.8 MB
    float*  ai      = (float*)alloc((size_t)N_NODES * HEADS * 4);      // 1.6 MB
    float*  aj      = (float*)alloc((size_t)N_NODES * HEADS * 4);      // 1.6 MB
    float*  wiwj    = (float*)alloc((size_t)IN_F * 8 * 4);             // 4 KB
    int*    scursor = (int*)alloc((size_t)NSLICES * 4);                // 1.6 KB
    int2*   seg     = (int2*)alloc((size_t)NSLICES * SEG_CAP * 8);     // 14.4 MB

    prep_kernel<<<(IN_F * 8 + 255) / 256, 256, 0, stream>>>(
        W, att_i, att_j, wiwj, scursor);
    proj_bin_kernel<<<TOTAL_BLOCKS, 256, 0, stream>>>(
        x, W, wiwj, ei, hb, ai, aj, scursor, seg);
    agg_kernel<<<NSLICES * 4, 512, 0, stream>>>(seg, scursor, hb, ai, aj, out);
}